// Round 7
// baseline (354.345 us; speedup 1.0000x reference)
//
#include <hip/hip_runtime.h>

// GCN: 3x (GEMM 128x128 + normalized scatter-sum) + mean-pool + linear + softmax.
// R1: two-stage pool. R2: parallel scan. R3: bf16 + split-W MFMA GEMM.
// R4: agg 8-edges-in-flight; h pre-scaled by dinv (edges carry only src index).
// R5: CSR via two-level bucket sort (contiguous writes, no 64B-line blowup).
// R6: fuse agg(l)+gemm(l+1) — agg row i feeds only gemm row i, so blocks
//     aggregate their 64 rows straight into the LDS A-tile (skip abuf
//     round-trip, -51MB traffic, -2 dispatches); 3x repack -> 1 launch.
// Assumes n <= 65536 (src packed u16) and n <= 512*128 (bucket count cap).

#define NF 128
#define MAXBUCK 512
#define L1_CHUNK 8192
#define L1_THREADS 512
#define L1_PER_THREAD 16   // L1_CHUNK / L1_THREADS
#define D_CAP 4608         // max edges per bucket (mean 2176)

typedef __attribute__((ext_vector_type(8))) short short8;
typedef __attribute__((ext_vector_type(4))) float floatx4;

__device__ __forceinline__ unsigned int bf16_rne(float x) {
    unsigned int u = __float_as_uint(x);
    return (u + 0x7fffu + ((u >> 16) & 1u)) >> 16;
}
__device__ __forceinline__ unsigned int pack_bf16_rne(float x, float y) {
    return bf16_rne(x) | (bf16_rne(y) << 16);
}

// ---- CSR build A: coarse bucket histogram (bucket = dst>>7) ----
__global__ __launch_bounds__(256) void k_bcount(const int* __restrict__ colv,
                                                int* __restrict__ bucket_cnt,
                                                int ne, int etot, int nbuck) {
    __shared__ int h[MAXBUCK];
    for (int i = threadIdx.x; i < MAXBUCK; i += 256) h[i] = 0;
    __syncthreads();
    int stride = gridDim.x * 256;
    for (int e = blockIdx.x * 256 + threadIdx.x; e < etot; e += stride) {
        int d = (e < ne) ? colv[e] : (e - ne);
        atomicAdd(&h[d >> 7], 1);
    }
    __syncthreads();
    for (int i = threadIdx.x; i < nbuck; i += 256) {
        int v = h[i];
        if (v) atomicAdd(&bucket_cnt[i], v);
    }
}

// ---- CSR build B: scan bucket counts -> bases & cursors; also offsets[n] ----
__global__ __launch_bounds__(MAXBUCK) void k_bscan(const int* __restrict__ bucket_cnt,
                                                   int* __restrict__ bucket_base,
                                                   int* __restrict__ bucket_cursor,
                                                   int* __restrict__ offsets,
                                                   int etot, int n, int nbuck) {
    __shared__ int sh[MAXBUCK];
    int t = threadIdx.x;
    int v = (t < nbuck) ? bucket_cnt[t] : 0;
    sh[t] = v;
    __syncthreads();
    #pragma unroll
    for (int off = 1; off < MAXBUCK; off <<= 1) {
        int add = (t >= off) ? sh[t - off] : 0;
        __syncthreads();
        sh[t] += add;
        __syncthreads();
    }
    if (t < nbuck) { int b = sh[t] - v; bucket_base[t] = b; bucket_cursor[t] = b; }
    if (t == 0) { bucket_base[nbuck] = etot; offsets[n] = etot; }
}

// ---- CSR build C: bucket-grouped scatter via LDS reorder ----
__global__ __launch_bounds__(L1_THREADS) void k_bucket_scatter(
        const int* __restrict__ row, const int* __restrict__ colv,
        int* __restrict__ bucket_cursor, unsigned int* __restrict__ buck_arr,
        int ne, int etot, int nbuck) {
    __shared__ unsigned int hist[MAXBUCK];
    __shared__ unsigned int lbase[MAXBUCK];
    __shared__ unsigned int lcur[MAXBUCK];
    __shared__ unsigned int runb[MAXBUCK];
    __shared__ unsigned int sa[MAXBUCK], sb[MAXBUCK];
    __shared__ unsigned int reorder[L1_CHUNK];
    int t = threadIdx.x;
    int e0 = blockIdx.x * L1_CHUNK;
    int cnt_here = min(etot - e0, L1_CHUNK);

    hist[t] = 0;
    __syncthreads();

    unsigned int myv[L1_PER_THREAD];
    #pragma unroll
    for (int j = 0; j < L1_PER_THREAD; ++j) {
        int e = e0 + j * L1_THREADS + t;
        if (e < etot) {
            int s, d;
            if (e < ne) { s = row[e]; d = colv[e]; } else { s = d = e - ne; }
            myv[j] = (unsigned int)s | ((unsigned int)d << 16);
            atomicAdd(&hist[d >> 7], 1u);
        } else myv[j] = 0xffffffffu;
    }
    __syncthreads();

    sa[t] = hist[t];
    __syncthreads();
    unsigned int* pin = sa;
    unsigned int* pout = sb;
    #pragma unroll
    for (int off = 1; off < MAXBUCK; off <<= 1) {
        pout[t] = pin[t] + ((t >= off) ? pin[t - off] : 0);
        __syncthreads();
        unsigned int* tmp = pin; pin = pout; pout = tmp;
    }
    unsigned int ex = pin[t] - hist[t];
    lbase[t] = ex;
    lcur[t]  = ex;
    if (t < nbuck && hist[t] > 0)
        runb[t] = (unsigned int)atomicAdd(&bucket_cursor[t], (int)hist[t]);
    __syncthreads();

    #pragma unroll
    for (int j = 0; j < L1_PER_THREAD; ++j) {
        unsigned int v = myv[j];
        if (v != 0xffffffffu) {
            unsigned int p = atomicAdd(&lcur[v >> 23], 1u);
            reorder[p] = v;
        }
    }
    __syncthreads();

    for (int i = t; i < cnt_here; i += L1_THREADS) {
        unsigned int v = reorder[i];
        unsigned int b = v >> 23;
        buck_arr[runb[b] + ((unsigned int)i - lbase[b])] = v;
    }
}

// ---- CSR build D: per-bucket fine sort; emits src16, offsets, dinv ----
__global__ __launch_bounds__(256) void k_fine(const unsigned int* __restrict__ buck_arr,
                                              const int* __restrict__ bucket_base,
                                              int* __restrict__ offsets,
                                              float* __restrict__ dinv,
                                              unsigned short* __restrict__ src16,
                                              int n) {
    int b = blockIdx.x;
    int base = bucket_base[b];
    int m = min(bucket_base[b + 1] - base, D_CAP);
    int node0 = b << 7;
    int nn = min(128, n - node0);
    __shared__ unsigned int cnt[128];
    __shared__ unsigned int lsc[256];
    __shared__ unsigned int lcur[128];
    __shared__ unsigned short srcbuf[D_CAP];
    int t = threadIdx.x;
    if (t < 128) cnt[t] = 0;
    __syncthreads();
    for (int i = t; i < m; i += 256)
        atomicAdd(&cnt[(buck_arr[base + i] >> 16) - node0], 1u);
    __syncthreads();
    unsigned int v0 = (t < 128) ? cnt[t] : 0;
    lsc[t] = v0;
    __syncthreads();
    #pragma unroll
    for (int off = 1; off < 128; off <<= 1) {
        unsigned int add = (t >= off) ? lsc[t - off] : 0;
        __syncthreads();
        lsc[t] += add;
        __syncthreads();
    }
    if (t < 128) {
        unsigned int ex = lsc[t] - v0;
        lcur[t] = ex;
        if (t < nn) {
            offsets[node0 + t] = base + (int)ex;
            dinv[node0 + t] = rsqrtf((float)v0);
        }
    }
    __syncthreads();
    for (int i = t; i < m; i += 256) {
        unsigned int v = buck_arr[base + i];
        unsigned int p = atomicAdd(&lcur[(v >> 16) - node0], 1u);
        srcbuf[p] = (unsigned short)(v & 0xffffu);
    }
    __syncthreads();
    for (int i = t; i < m; i += 256)
        src16[base + i] = srcbuf[i];
}

// ---- repack all 3 W (fp32 [k][n]) into B-fragment-major bf16 hi/lo.
// 24 blocks: blockIdx>>3 selects weight; slabs of NF*NF in whi/wlo. ----
__global__ __launch_bounds__(256) void k_repack_w3(const float* __restrict__ W0,
                                                   const float* __restrict__ W1,
                                                   const float* __restrict__ W2,
                                                   unsigned short* __restrict__ whi,
                                                   unsigned short* __restrict__ wlo) {
    int wsel = blockIdx.x >> 3;
    const float* W = (wsel == 0) ? W0 : (wsel == 1) ? W1 : W2;
    int idx = (blockIdx.x & 7) * 256 + threadIdx.x;  // 0..2047
    int slab = wsel * NF * NF;
    int l = idx & 63;
    int t = (idx >> 6) & 7;
    int s = idx >> 9;
    int kbase = s * 32 + (l >> 4) * 8;
    int nn = t * 16 + (l & 15);
    #pragma unroll
    for (int j = 0; j < 8; ++j) {
        float w = W[(kbase + j) * NF + nn];
        unsigned int h = bf16_rne(w);
        float hf = __uint_as_float(h << 16);
        unsigned int lo = bf16_rne(w - hf);
        whi[slab + idx * 8 + j] = (unsigned short)h;
        wlo[slab + idx * 8 + j] = (unsigned short)lo;
    }
}

// ---- GEMM: Out[M,128](bf16, pre-scaled by dinv[row]) = A @ (Whi+Wlo).
// Used only for layer 0 (A = fp32 x). ----
__global__ __launch_bounds__(256) void k_gemm_mfma(const float* __restrict__ Af,
                                                   const unsigned short* __restrict__ Whi,
                                                   const unsigned short* __restrict__ Wlo,
                                                   const float* __restrict__ dinv,
                                                   unsigned short* __restrict__ Out,
                                                   int M) {
    __shared__ unsigned short As[64 * 136];
    int tid = threadIdx.x;
    int row0 = blockIdx.x * 64;

    for (int c = tid; c < 1024; c += 256) {
        int r = c >> 4, off = c & 15;
        int gr = min(row0 + r, M - 1);
        const float4* p = (const float4*)(Af + (size_t)gr * NF) + off * 2;
        float4 v0 = p[0], v1 = p[1];
        uint4 pk;
        pk.x = pack_bf16_rne(v0.x, v0.y);
        pk.y = pack_bf16_rne(v0.z, v0.w);
        pk.z = pack_bf16_rne(v1.x, v1.y);
        pk.w = pack_bf16_rne(v1.z, v1.w);
        *(uint4*)(&As[r * 136 + off * 8]) = pk;
    }
    __syncthreads();

    int wave = tid >> 6, l = tid & 63;
    int q = l >> 4, c16 = l & 15;
    int wrow0 = wave * 16;

    floatx4 acc[8];
    #pragma unroll
    for (int t = 0; t < 8; ++t) acc[t] = (floatx4){0.f, 0.f, 0.f, 0.f};

    #pragma unroll
    for (int s = 0; s < 4; ++s) {
        short8 a = *(const short8*)(&As[(wrow0 + c16) * 136 + s * 32 + q * 8]);
        #pragma unroll
        for (int t = 0; t < 8; ++t) {
            short8 bh = *(const short8*)(Whi + ((size_t)((s * 8 + t) * 64 + l) * 8));
            acc[t] = __builtin_amdgcn_mfma_f32_16x16x32_bf16(a, bh, acc[t], 0, 0, 0);
            short8 bl = *(const short8*)(Wlo + ((size_t)((s * 8 + t) * 64 + l) * 8));
            acc[t] = __builtin_amdgcn_mfma_f32_16x16x32_bf16(a, bl, acc[t], 0, 0, 0);
        }
    }

    float ds[4];
    #pragma unroll
    for (int i = 0; i < 4; ++i) {
        int gr = row0 + wrow0 + q * 4 + i;
        ds[i] = (gr < M) ? dinv[gr] : 0.f;
    }
    #pragma unroll
    for (int t = 0; t < 8; ++t) {
        #pragma unroll
        for (int i = 0; i < 4; ++i) {
            int gr = row0 + wrow0 + q * 4 + i;
            if (gr < M)
                Out[(size_t)gr * NF + t * 16 + c16] =
                    (unsigned short)bf16_rne(acc[t][i] * ds[i]);
        }
    }
}

// ---- FUSED agg + gemm: block owns 64 rows. Phase 1: each wave aggregates
// its 16 nodes (8 edges in flight), applies dinv*sum+b, relu, writes bf16
// row into LDS A-tile. Phase 2: standard MFMA vs (Whi+Wlo), epilogue
// pre-scales by dinv for the NEXT layer's gather. ----
__global__ __launch_bounds__(256) void k_agg_gemm(const unsigned short* __restrict__ hs,
                                                  const int* __restrict__ offsets,
                                                  const unsigned short* __restrict__ src16,
                                                  const float* __restrict__ dinv,
                                                  const float* __restrict__ bias,
                                                  const unsigned short* __restrict__ Whi,
                                                  const unsigned short* __restrict__ Wlo,
                                                  unsigned short* __restrict__ Out,
                                                  int M) {
    __shared__ unsigned short As[64 * 136];
    int tid = threadIdx.x;
    int wave = tid >> 6, l = tid & 63;
    int g = l >> 4, f = l & 15;
    int row0 = blockIdx.x * 64;
    const uint4* h4 = (const uint4*)hs;

    for (int k = 0; k < 16; ++k) {
        int node = row0 + wave * 16 + k;
        float acc[8];
        #pragma unroll
        for (int j = 0; j < 8; ++j) acc[j] = 0.f;
        if (node < M) {
            int start = offsets[node], end = offsets[node + 1];
            for (int base = start; base < end; base += 8) {
                int e0 = base + g;
                int e1 = e0 + 4;
                bool v0 = e0 < end, v1 = e1 < end;
                int i0 = v0 ? e0 : start;
                int i1 = v1 ? e1 : start;
                int s0 = (int)src16[i0];
                int s1 = (int)src16[i1];
                float m0 = v0 ? 1.f : 0.f;
                float m1 = v1 ? 1.f : 0.f;
                uint4 r0 = h4[(size_t)s0 * 16 + f];
                uint4 r1 = h4[(size_t)s1 * 16 + f];
                const unsigned int* w0 = (const unsigned int*)&r0;
                const unsigned int* w1 = (const unsigned int*)&r1;
                #pragma unroll
                for (int kk = 0; kk < 4; ++kk) {
                    acc[2 * kk]     = fmaf(m0, __uint_as_float(w0[kk] << 16),         acc[2 * kk]);
                    acc[2 * kk + 1] = fmaf(m0, __uint_as_float(w0[kk] & 0xffff0000u), acc[2 * kk + 1]);
                    acc[2 * kk]     = fmaf(m1, __uint_as_float(w1[kk] << 16),         acc[2 * kk]);
                    acc[2 * kk + 1] = fmaf(m1, __uint_as_float(w1[kk] & 0xffff0000u), acc[2 * kk + 1]);
                }
            }
        }
        #pragma unroll
        for (int j = 0; j < 8; ++j) {
            acc[j] += __shfl_xor(acc[j], 16);
            acc[j] += __shfl_xor(acc[j], 32);
        }
        if (g == 0) {
            float dd = (node < M) ? dinv[node] : 0.f;
            float4 b0 = ((const float4*)bias)[2 * f];
            float4 b1 = ((const float4*)bias)[2 * f + 1];
            float r[8];
            r[0] = fmaf(dd, acc[0], b0.x); r[1] = fmaf(dd, acc[1], b0.y);
            r[2] = fmaf(dd, acc[2], b0.z); r[3] = fmaf(dd, acc[3], b0.w);
            r[4] = fmaf(dd, acc[4], b1.x); r[5] = fmaf(dd, acc[5], b1.y);
            r[6] = fmaf(dd, acc[6], b1.z); r[7] = fmaf(dd, acc[7], b1.w);
            #pragma unroll
            for (int j = 0; j < 8; ++j) r[j] = fmaxf(r[j], 0.f);  // fused layers always relu
            uint4 pk;
            pk.x = pack_bf16_rne(r[0], r[1]);
            pk.y = pack_bf16_rne(r[2], r[3]);
            pk.z = pack_bf16_rne(r[4], r[5]);
            pk.w = pack_bf16_rne(r[6], r[7]);
            *(uint4*)(&As[(wave * 16 + k) * 136 + f * 8]) = pk;
        }
    }
    __syncthreads();

    int q = l >> 4, c16 = l & 15;
    int wrow0 = wave * 16;

    floatx4 acc2[8];
    #pragma unroll
    for (int t = 0; t < 8; ++t) acc2[t] = (floatx4){0.f, 0.f, 0.f, 0.f};

    #pragma unroll
    for (int s = 0; s < 4; ++s) {
        short8 a = *(const short8*)(&As[(wrow0 + c16) * 136 + s * 32 + q * 8]);
        #pragma unroll
        for (int t = 0; t < 8; ++t) {
            short8 bh = *(const short8*)(Whi + ((size_t)((s * 8 + t) * 64 + l) * 8));
            acc2[t] = __builtin_amdgcn_mfma_f32_16x16x32_bf16(a, bh, acc2[t], 0, 0, 0);
            short8 bl = *(const short8*)(Wlo + ((size_t)((s * 8 + t) * 64 + l) * 8));
            acc2[t] = __builtin_amdgcn_mfma_f32_16x16x32_bf16(a, bl, acc2[t], 0, 0, 0);
        }
    }

    float ds[4];
    #pragma unroll
    for (int i = 0; i < 4; ++i) {
        int gr = row0 + wrow0 + q * 4 + i;
        ds[i] = (gr < M) ? dinv[gr] : 0.f;
    }
    #pragma unroll
    for (int t = 0; t < 8; ++t) {
        #pragma unroll
        for (int i = 0; i < 4; ++i) {
            int gr = row0 + wrow0 + q * 4 + i;
            if (gr < M)
                Out[(size_t)gr * NF + t * 16 + c16] =
                    (unsigned short)bf16_rne(acc2[t][i] * ds[i]);
        }
    }
}

// ---- standalone agg for the final layer (no relu), writes abuf for pool ----
__global__ __launch_bounds__(256) void k_agg_bf16(const unsigned short* __restrict__ hs,
                                                  const int* __restrict__ offsets,
                                                  const unsigned short* __restrict__ src16,
                                                  const float* __restrict__ dinv,
                                                  const float* __restrict__ bias,
                                                  unsigned short* __restrict__ out,
                                                  int n, int do_relu) {
    int wave = threadIdx.x >> 6;
    int lane = threadIdx.x & 63;
    int node = blockIdx.x * 4 + wave;
    if (node >= n) return;
    int g = lane >> 4;
    int f = lane & 15;
    int start = offsets[node], end = offsets[node + 1];

    const uint4* h4 = (const uint4*)hs;
    float acc[8];
    #pragma unroll
    for (int j = 0; j < 8; ++j) acc[j] = 0.f;

    for (int base = start; base < end; base += 8) {
        int e0 = base + g;
        int e1 = e0 + 4;
        bool v0 = e0 < end, v1 = e1 < end;
        int i0 = v0 ? e0 : start;
        int i1 = v1 ? e1 : start;
        int s0 = (int)src16[i0];
        int s1 = (int)src16[i1];
        float m0 = v0 ? 1.f : 0.f;
        float m1 = v1 ? 1.f : 0.f;
        uint4 r0 = h4[(size_t)s0 * 16 + f];
        uint4 r1 = h4[(size_t)s1 * 16 + f];
        const unsigned int* w0 = (const unsigned int*)&r0;
        const unsigned int* w1 = (const unsigned int*)&r1;
        #pragma unroll
        for (int k = 0; k < 4; ++k) {
            acc[2 * k]     = fmaf(m0, __uint_as_float(w0[k] << 16),         acc[2 * k]);
            acc[2 * k + 1] = fmaf(m0, __uint_as_float(w0[k] & 0xffff0000u), acc[2 * k + 1]);
            acc[2 * k]     = fmaf(m1, __uint_as_float(w1[k] << 16),         acc[2 * k]);
            acc[2 * k + 1] = fmaf(m1, __uint_as_float(w1[k] & 0xffff0000u), acc[2 * k + 1]);
        }
    }

    #pragma unroll
    for (int j = 0; j < 8; ++j) {
        acc[j] += __shfl_xor(acc[j], 16);
        acc[j] += __shfl_xor(acc[j], 32);
    }

    if (g == 0) {
        float dd = dinv[node];
        float4 b0 = ((const float4*)bias)[2 * f];
        float4 b1 = ((const float4*)bias)[2 * f + 1];
        float r[8];
        r[0] = fmaf(dd, acc[0], b0.x); r[1] = fmaf(dd, acc[1], b0.y);
        r[2] = fmaf(dd, acc[2], b0.z); r[3] = fmaf(dd, acc[3], b0.w);
        r[4] = fmaf(dd, acc[4], b1.x); r[5] = fmaf(dd, acc[5], b1.y);
        r[6] = fmaf(dd, acc[6], b1.z); r[7] = fmaf(dd, acc[7], b1.w);
        if (do_relu) {
            #pragma unroll
            for (int j = 0; j < 8; ++j) r[j] = fmaxf(r[j], 0.f);
        }
        uint4 pk;
        pk.x = pack_bf16_rne(r[0], r[1]);
        pk.y = pack_bf16_rne(r[2], r[3]);
        pk.z = pack_bf16_rne(r[4], r[5]);
        pk.w = pack_bf16_rne(r[6], r[7]);
        ((uint4*)out)[(size_t)node * 16 + f] = pk;
    }
}

// ---- pooling: register-accumulate per graph run (batch sorted) ----
__global__ __launch_bounds__(128) void k_pool_partial(const unsigned short* __restrict__ h,
                                                      const int* __restrict__ batch,
                                                      float* __restrict__ pooled,
                                                      int n, int chunk) {
    int t  = threadIdx.x;
    int i0 = blockIdx.x * chunk;
    if (i0 >= n) return;
    int i1 = min(n, i0 + chunk);
    int g  = batch[i0];
    float acc = 0.f;
    for (int i = i0; i < i1; ++i) {
        int bg = batch[i];
        if (bg != g) {
            atomicAdd(&pooled[g * NF + t], acc);
            acc = 0.f;
            g = bg;
        }
        acc += __uint_as_float((unsigned int)h[(size_t)i * NF + t] << 16);
    }
    atomicAdd(&pooled[g * NF + t], acc);
}

// ---- head: counts + linear 128x16 + softmax ----
__global__ __launch_bounds__(1024) void k_head(const float* __restrict__ pooled,
                                               const int* __restrict__ batch,
                                               const float* __restrict__ linW,
                                               const float* __restrict__ linb,
                                               float* __restrict__ out,
                                               int n) {
    int t = threadIdx.x;
    int g = t >> 4;
    int c = t & 15;

    int lo = 0, hi = n;
    while (lo < hi) { int mid = (lo + hi) >> 1; if (batch[mid] < g) lo = mid + 1; else hi = mid; }
    int start = lo;
    lo = start; hi = n;
    while (lo < hi) { int mid = (lo + hi) >> 1; if (batch[mid] < g + 1) lo = mid + 1; else hi = mid; }
    float inv_cnt = 1.f / fmaxf((float)(lo - start), 1.f);

    float acc = linb[c];
    for (int k = 0; k < NF; ++k)
        acc += pooled[g * NF + k] * inv_cnt * linW[k * 16 + c];

    float m = acc;
    #pragma unroll
    for (int s = 8; s >= 1; s >>= 1) m = fmaxf(m, __shfl_xor(m, s, 16));
    float e = expf(acc - m);
    float ssum = e;
    #pragma unroll
    for (int s = 8; s >= 1; s >>= 1) ssum += __shfl_xor(ssum, s, 16);
    out[g * 16 + c] = e / ssum;
}

extern "C" void kernel_launch(void* const* d_in, const int* in_sizes, int n_in,
                              void* d_out, int out_size, void* d_ws, size_t ws_size,
                              hipStream_t stream) {
    const float* x    = (const float*)d_in[0];
    const int*   edge = (const int*)d_in[1];
    const int*   batch= (const int*)d_in[2];
    const float* W0   = (const float*)d_in[3];
    const float* b0   = (const float*)d_in[4];
    const float* W1   = (const float*)d_in[5];
    const float* b1   = (const float*)d_in[6];
    const float* W2   = (const float*)d_in[7];
    const float* b2   = (const float*)d_in[8];
    const float* linW = (const float*)d_in[9];
    const float* linb = (const float*)d_in[10];

    int n  = in_sizes[0] / NF;       // 50000
    int ne = in_sizes[1] / 2;        // 800000
    int n_graphs = out_size / 16;    // 64
    const int* row  = edge;
    const int* colv = edge + ne;
    int etot = ne + n;
    int nbuck = (n + 127) >> 7;      // 391

    char* p = (char*)d_ws;
    auto alloc = [&](size_t bytes) { char* r = p; p += (bytes + 255) & ~(size_t)255; return r; };
    int*   bucket_cnt    = (int*)alloc((size_t)MAXBUCK * 4);
    int*   bucket_base   = (int*)alloc((size_t)(MAXBUCK + 1) * 4);
    int*   bucket_cursor = (int*)alloc((size_t)MAXBUCK * 4);
    unsigned int* buck_arr = (unsigned int*)alloc((size_t)etot * 4);
    unsigned short* src16  = (unsigned short*)alloc((size_t)etot * 2);
    int*   offsets = (int*)  alloc((size_t)(n + 1) * 4);
    float* dinv    = (float*)alloc((size_t)n * 4);
    unsigned short* gbuf  = (unsigned short*)alloc((size_t)n * NF * 2);
    unsigned short* gbuf2 = (unsigned short*)alloc((size_t)n * NF * 2);
    unsigned short* abuf  = (unsigned short*)alloc((size_t)n * NF * 2);
    float* pooled  = (float*)alloc((size_t)n_graphs * NF * 4);
    unsigned short* whi = (unsigned short*)alloc((size_t)3 * NF * NF * 2);
    unsigned short* wlo = (unsigned short*)alloc((size_t)3 * NF * NF * 2);

    // CSR build (two-level bucket sort)
    hipMemsetAsync(bucket_cnt, 0, (size_t)MAXBUCK * 4, stream);
    k_bcount<<<128, 256, 0, stream>>>(colv, bucket_cnt, ne, etot, nbuck);
    k_bscan<<<1, MAXBUCK, 0, stream>>>(bucket_cnt, bucket_base, bucket_cursor,
                                       offsets, etot, n, nbuck);
    k_bucket_scatter<<<(etot + L1_CHUNK - 1) / L1_CHUNK, L1_THREADS, 0, stream>>>(
        row, colv, bucket_cursor, buck_arr, ne, etot, nbuck);
    k_fine<<<nbuck, 256, 0, stream>>>(buck_arr, bucket_base, offsets, dinv, src16, n);

    // weight repack (hi/lo split), all 3 in one launch
    k_repack_w3<<<24, 256, 0, stream>>>(W0, W1, W2, whi, wlo);

    int gemm_blocks = (n + 63) / 64;
    int agg_blocks  = (n + 3) / 4;
    const size_t WSLAB = (size_t)NF * NF;

    // layer 0 gemm; then fused agg0+gemm1, agg1+gemm2; final agg2
    k_gemm_mfma<<<gemm_blocks, 256, 0, stream>>>(x, whi, wlo, dinv, gbuf, n);
    k_agg_gemm<<<gemm_blocks, 256, 0, stream>>>(gbuf, offsets, src16, dinv, b0,
                                                whi + WSLAB, wlo + WSLAB, gbuf2, n);
    k_agg_gemm<<<gemm_blocks, 256, 0, stream>>>(gbuf2, offsets, src16, dinv, b1,
                                                whi + 2 * WSLAB, wlo + 2 * WSLAB, gbuf, n);
    k_agg_bf16<<<agg_blocks, 256, 0, stream>>>(gbuf, offsets, src16, dinv, b2, abuf, n, 0);

    // pool + head
    hipMemsetAsync(pooled, 0, (size_t)n_graphs * NF * 4, stream);
    int pool_blocks = 400;
    int pool_chunk  = (n + pool_blocks - 1) / pool_blocks;
    k_pool_partial<<<pool_blocks, 128, 0, stream>>>(abuf, batch, pooled, n, pool_chunk);
    k_head<<<1, 1024, 0, stream>>>(pooled, batch, linW, linb, (float*)d_out, n);
}

// Round 8
// 319.879 us; speedup vs baseline: 1.1077x; 1.1077x over previous
//
#include <hip/hip_runtime.h>

// GCN: 3x (GEMM 128x128 + normalized scatter-sum) + mean-pool + linear + softmax.
// R1: two-stage pool. R2: parallel scan. R3: bf16 + split-W MFMA GEMM.
// R4: agg multi-edge-in-flight; h pre-scaled by dinv (edges carry only src idx).
// R5: CSR via two-level bucket sort (contiguous writes, no 64B-line blowup).
// R6 FAILED: agg+gemm fusion cut gather parallelism 16x (occ 68%->28%) — reverted.
// R7: agg 16 edges in flight (was 8); CSR bucket slabs with fixed CAP so the
//     bcount+bscan kernels vanish (bucket_base = b*CAP, per-node starts/ends).
// Assumes n <= 65536 (src packed u16), n <= 512*128, bucket load < CAP (8.5σ).

#define NF 128
#define MAXBUCK 512
#define CAP 2560           // slab capacity per bucket (mean 2176, sigma ~45)
#define L1_CHUNK 8192
#define L1_THREADS 512
#define L1_PER_THREAD 16   // L1_CHUNK / L1_THREADS

typedef __attribute__((ext_vector_type(8))) short short8;
typedef __attribute__((ext_vector_type(4))) float floatx4;

__device__ __forceinline__ unsigned int bf16_rne(float x) {
    unsigned int u = __float_as_uint(x);
    return (u + 0x7fffu + ((u >> 16) & 1u)) >> 16;
}
__device__ __forceinline__ unsigned int pack_bf16_rne(float x, float y) {
    return bf16_rne(x) | (bf16_rne(y) << 16);
}

// ---- CSR A: init slab cursors ----
__global__ void k_binit(int* __restrict__ cursor, int nbuck) {
    int i = blockIdx.x * blockDim.x + threadIdx.x;
    if (i <= nbuck) cursor[i] = i * CAP;
}

// ---- CSR B: bucket-grouped scatter into fixed slabs via LDS reorder ----
__global__ __launch_bounds__(L1_THREADS) void k_bucket_scatter(
        const int* __restrict__ row, const int* __restrict__ colv,
        int* __restrict__ bucket_cursor, unsigned int* __restrict__ buck_arr,
        int ne, int etot, int nbuck) {
    __shared__ unsigned int hist[MAXBUCK];
    __shared__ unsigned int lbase[MAXBUCK];
    __shared__ unsigned int lcur[MAXBUCK];
    __shared__ unsigned int runb[MAXBUCK];
    __shared__ unsigned int sa[MAXBUCK], sb[MAXBUCK];
    __shared__ unsigned int reorder[L1_CHUNK];
    int t = threadIdx.x;
    int e0 = blockIdx.x * L1_CHUNK;
    int cnt_here = min(etot - e0, L1_CHUNK);

    hist[t] = 0;
    __syncthreads();

    unsigned int myv[L1_PER_THREAD];
    #pragma unroll
    for (int j = 0; j < L1_PER_THREAD; ++j) {
        int e = e0 + j * L1_THREADS + t;
        if (e < etot) {
            int s, d;
            if (e < ne) { s = row[e]; d = colv[e]; } else { s = d = e - ne; }
            myv[j] = (unsigned int)s | ((unsigned int)d << 16);
            atomicAdd(&hist[d >> 7], 1u);
        } else myv[j] = 0xffffffffu;
    }
    __syncthreads();

    sa[t] = hist[t];
    __syncthreads();
    unsigned int* pin = sa;
    unsigned int* pout = sb;
    #pragma unroll
    for (int off = 1; off < MAXBUCK; off <<= 1) {
        pout[t] = pin[t] + ((t >= off) ? pin[t - off] : 0);
        __syncthreads();
        unsigned int* tmp = pin; pin = pout; pout = tmp;
    }
    unsigned int ex = pin[t] - hist[t];
    lbase[t] = ex;
    lcur[t]  = ex;
    if (t < nbuck && hist[t] > 0)
        runb[t] = (unsigned int)atomicAdd(&bucket_cursor[t], (int)hist[t]);
    __syncthreads();

    #pragma unroll
    for (int j = 0; j < L1_PER_THREAD; ++j) {
        unsigned int v = myv[j];
        if (v != 0xffffffffu) {
            unsigned int p = atomicAdd(&lcur[v >> 23], 1u);
            reorder[p] = v;
        }
    }
    __syncthreads();

    for (int i = t; i < cnt_here; i += L1_THREADS) {
        unsigned int v = reorder[i];
        unsigned int b = v >> 23;
        buck_arr[runb[b] + ((unsigned int)i - lbase[b])] = v;
    }
}

// ---- CSR C: per-bucket fine sort; emits src16 (slab-local), starts/ends/dinv ----
__global__ __launch_bounds__(256) void k_fine(const unsigned int* __restrict__ buck_arr,
                                              const int* __restrict__ bucket_cursor,
                                              int* __restrict__ starts,
                                              int* __restrict__ ends,
                                              float* __restrict__ dinv,
                                              unsigned short* __restrict__ src16,
                                              int n) {
    int b = blockIdx.x;
    int base = b * CAP;
    int m = min(bucket_cursor[b] - base, CAP);
    int node0 = b << 7;
    int nn = min(128, n - node0);
    __shared__ unsigned int cnt[128];
    __shared__ unsigned int lsc[256];
    __shared__ unsigned int lcur[128];
    __shared__ unsigned short srcbuf[CAP];
    int t = threadIdx.x;
    if (t < 128) cnt[t] = 0;
    __syncthreads();
    for (int i = t; i < m; i += 256)
        atomicAdd(&cnt[(buck_arr[base + i] >> 16) - node0], 1u);
    __syncthreads();
    unsigned int v0 = (t < 128) ? cnt[t] : 0;
    lsc[t] = v0;
    __syncthreads();
    #pragma unroll
    for (int off = 1; off < 128; off <<= 1) {
        unsigned int add = (t >= off) ? lsc[t - off] : 0;
        __syncthreads();
        lsc[t] += add;
        __syncthreads();
    }
    if (t < 128) {
        unsigned int ex = lsc[t] - v0;
        lcur[t] = ex;
        if (t < nn) {
            starts[node0 + t] = base + (int)ex;
            ends[node0 + t]   = base + (int)(ex + v0);
            dinv[node0 + t]   = rsqrtf((float)v0);   // deg >= 1 (self-loop)
        }
    }
    __syncthreads();
    for (int i = t; i < m; i += 256) {
        unsigned int v = buck_arr[base + i];
        unsigned int p = atomicAdd(&lcur[(v >> 16) - node0], 1u);
        srcbuf[p] = (unsigned short)(v & 0xffffu);
    }
    __syncthreads();
    for (int i = t; i < m; i += 256)
        src16[base + i] = srcbuf[i];
}

// ---- repack all 3 W (fp32 [k][n]) into B-fragment-major bf16 hi/lo ----
__global__ __launch_bounds__(256) void k_repack_w3(const float* __restrict__ W0,
                                                   const float* __restrict__ W1,
                                                   const float* __restrict__ W2,
                                                   unsigned short* __restrict__ whi,
                                                   unsigned short* __restrict__ wlo) {
    int wsel = blockIdx.x >> 3;
    const float* W = (wsel == 0) ? W0 : (wsel == 1) ? W1 : W2;
    int idx = (blockIdx.x & 7) * 256 + threadIdx.x;  // 0..2047
    int slab = wsel * NF * NF;
    int l = idx & 63;
    int t = (idx >> 6) & 7;
    int s = idx >> 9;
    int kbase = s * 32 + (l >> 4) * 8;
    int nn = t * 16 + (l & 15);
    #pragma unroll
    for (int j = 0; j < 8; ++j) {
        float w = W[(kbase + j) * NF + nn];
        unsigned int h = bf16_rne(w);
        float hf = __uint_as_float(h << 16);
        unsigned int lo = bf16_rne(w - hf);
        whi[slab + idx * 8 + j] = (unsigned short)h;
        wlo[slab + idx * 8 + j] = (unsigned short)lo;
    }
}

// ---- GEMM: Out[M,128](bf16, pre-scaled by dinv[row]) = A @ (Whi+Wlo).
// Af fp32 path (layer 0) or Ab bf16 path (layers 1,2). ----
__global__ __launch_bounds__(256) void k_gemm_mfma(const float* __restrict__ Af,
                                                   const unsigned short* __restrict__ Ab,
                                                   const unsigned short* __restrict__ Whi,
                                                   const unsigned short* __restrict__ Wlo,
                                                   const float* __restrict__ dinv,
                                                   unsigned short* __restrict__ Out,
                                                   int M) {
    __shared__ unsigned short As[64 * 136];
    int tid = threadIdx.x;
    int row0 = blockIdx.x * 64;

    if (Af) {
        for (int c = tid; c < 1024; c += 256) {
            int r = c >> 4, off = c & 15;
            int gr = min(row0 + r, M - 1);
            const float4* p = (const float4*)(Af + (size_t)gr * NF) + off * 2;
            float4 v0 = p[0], v1 = p[1];
            uint4 pk;
            pk.x = pack_bf16_rne(v0.x, v0.y);
            pk.y = pack_bf16_rne(v0.z, v0.w);
            pk.z = pack_bf16_rne(v1.x, v1.y);
            pk.w = pack_bf16_rne(v1.z, v1.w);
            *(uint4*)(&As[r * 136 + off * 8]) = pk;
        }
    } else {
        for (int c = tid; c < 1024; c += 256) {
            int r = c >> 4, off = c & 15;
            int gr = min(row0 + r, M - 1);
            *(uint4*)(&As[r * 136 + off * 8]) = ((const uint4*)(Ab + (size_t)gr * NF))[off];
        }
    }
    __syncthreads();

    int wave = tid >> 6, l = tid & 63;
    int q = l >> 4, c16 = l & 15;
    int wrow0 = wave * 16;

    floatx4 acc[8];
    #pragma unroll
    for (int t = 0; t < 8; ++t) acc[t] = (floatx4){0.f, 0.f, 0.f, 0.f};

    #pragma unroll
    for (int s = 0; s < 4; ++s) {
        short8 a = *(const short8*)(&As[(wrow0 + c16) * 136 + s * 32 + q * 8]);
        #pragma unroll
        for (int t = 0; t < 8; ++t) {
            short8 bh = *(const short8*)(Whi + ((size_t)((s * 8 + t) * 64 + l) * 8));
            acc[t] = __builtin_amdgcn_mfma_f32_16x16x32_bf16(a, bh, acc[t], 0, 0, 0);
            short8 bl = *(const short8*)(Wlo + ((size_t)((s * 8 + t) * 64 + l) * 8));
            acc[t] = __builtin_amdgcn_mfma_f32_16x16x32_bf16(a, bl, acc[t], 0, 0, 0);
        }
    }

    float ds[4];
    #pragma unroll
    for (int i = 0; i < 4; ++i) {
        int gr = row0 + wrow0 + q * 4 + i;
        ds[i] = (gr < M) ? dinv[gr] : 0.f;
    }
    #pragma unroll
    for (int t = 0; t < 8; ++t) {
        #pragma unroll
        for (int i = 0; i < 4; ++i) {
            int gr = row0 + wrow0 + q * 4 + i;
            if (gr < M)
                Out[(size_t)gr * NF + t * 16 + c16] =
                    (unsigned short)bf16_rne(acc[t][i] * ds[i]);
        }
    }
}

// ---- out[i] = relu?( dinv[i] * sum_e h'[src_e] + b ). One wave/node;
// lane = (slot g=l>>4, feat f=l&15); uint4/lane; 4 slots x unroll 4 =
// 16 edges in flight. Tail via 0/1 fma mask. ----
__global__ __launch_bounds__(256) void k_agg_bf16(const unsigned short* __restrict__ hs,
                                                  const int* __restrict__ starts,
                                                  const int* __restrict__ ends,
                                                  const unsigned short* __restrict__ src16,
                                                  const float* __restrict__ dinv,
                                                  const float* __restrict__ bias,
                                                  unsigned short* __restrict__ out,
                                                  int n, int do_relu) {
    int wave = threadIdx.x >> 6;
    int lane = threadIdx.x & 63;
    int node = blockIdx.x * 4 + wave;
    if (node >= n) return;
    int g = lane >> 4;
    int f = lane & 15;
    int start = starts[node], end = ends[node];

    const uint4* h4 = (const uint4*)hs;
    float acc[8];
    #pragma unroll
    for (int j = 0; j < 8; ++j) acc[j] = 0.f;

    for (int base = start; base < end; base += 16) {
        int   sidx[4];
        float msk[4];
        #pragma unroll
        for (int j = 0; j < 4; ++j) {
            int e = base + g + 4 * j;
            bool v = e < end;
            sidx[j] = (int)src16[v ? e : start];
            msk[j]  = v ? 1.f : 0.f;
        }
        uint4 rr[4];
        #pragma unroll
        for (int j = 0; j < 4; ++j)
            rr[j] = h4[(size_t)sidx[j] * 16 + f];
        #pragma unroll
        for (int j = 0; j < 4; ++j) {
            const unsigned int* w = (const unsigned int*)&rr[j];
            float m = msk[j];
            #pragma unroll
            for (int k = 0; k < 4; ++k) {
                acc[2 * k]     = fmaf(m, __uint_as_float(w[k] << 16),         acc[2 * k]);
                acc[2 * k + 1] = fmaf(m, __uint_as_float(w[k] & 0xffff0000u), acc[2 * k + 1]);
            }
        }
    }

    // fold the 4 edge slots (lanes 16 apart hold the same feat group)
    #pragma unroll
    for (int j = 0; j < 8; ++j) {
        acc[j] += __shfl_xor(acc[j], 16);
        acc[j] += __shfl_xor(acc[j], 32);
    }

    if (g == 0) {
        float dd = dinv[node];
        float4 b0 = ((const float4*)bias)[2 * f];
        float4 b1 = ((const float4*)bias)[2 * f + 1];
        float r[8];
        r[0] = fmaf(dd, acc[0], b0.x); r[1] = fmaf(dd, acc[1], b0.y);
        r[2] = fmaf(dd, acc[2], b0.z); r[3] = fmaf(dd, acc[3], b0.w);
        r[4] = fmaf(dd, acc[4], b1.x); r[5] = fmaf(dd, acc[5], b1.y);
        r[6] = fmaf(dd, acc[6], b1.z); r[7] = fmaf(dd, acc[7], b1.w);
        if (do_relu) {
            #pragma unroll
            for (int j = 0; j < 8; ++j) r[j] = fmaxf(r[j], 0.f);
        }
        uint4 pk;
        pk.x = pack_bf16_rne(r[0], r[1]);
        pk.y = pack_bf16_rne(r[2], r[3]);
        pk.z = pack_bf16_rne(r[4], r[5]);
        pk.w = pack_bf16_rne(r[6], r[7]);
        ((uint4*)out)[(size_t)node * 16 + f] = pk;
    }
}

// ---- pooling: register-accumulate per graph run (batch sorted) ----
__global__ __launch_bounds__(128) void k_pool_partial(const unsigned short* __restrict__ h,
                                                      const int* __restrict__ batch,
                                                      float* __restrict__ pooled,
                                                      int n, int chunk) {
    int t  = threadIdx.x;
    int i0 = blockIdx.x * chunk;
    if (i0 >= n) return;
    int i1 = min(n, i0 + chunk);
    int g  = batch[i0];
    float acc = 0.f;
    for (int i = i0; i < i1; ++i) {
        int bg = batch[i];
        if (bg != g) {
            atomicAdd(&pooled[g * NF + t], acc);
            acc = 0.f;
            g = bg;
        }
        acc += __uint_as_float((unsigned int)h[(size_t)i * NF + t] << 16);
    }
    atomicAdd(&pooled[g * NF + t], acc);
}

// ---- head: counts + linear 128x16 + softmax ----
__global__ __launch_bounds__(1024) void k_head(const float* __restrict__ pooled,
                                               const int* __restrict__ batch,
                                               const float* __restrict__ linW,
                                               const float* __restrict__ linb,
                                               float* __restrict__ out,
                                               int n) {
    int t = threadIdx.x;
    int g = t >> 4;
    int c = t & 15;

    int lo = 0, hi = n;
    while (lo < hi) { int mid = (lo + hi) >> 1; if (batch[mid] < g) lo = mid + 1; else hi = mid; }
    int start = lo;
    lo = start; hi = n;
    while (lo < hi) { int mid = (lo + hi) >> 1; if (batch[mid] < g + 1) lo = mid + 1; else hi = mid; }
    float inv_cnt = 1.f / fmaxf((float)(lo - start), 1.f);

    float acc = linb[c];
    for (int k = 0; k < NF; ++k)
        acc += pooled[g * NF + k] * inv_cnt * linW[k * 16 + c];

    float m = acc;
    #pragma unroll
    for (int s = 8; s >= 1; s >>= 1) m = fmaxf(m, __shfl_xor(m, s, 16));
    float e = expf(acc - m);
    float ssum = e;
    #pragma unroll
    for (int s = 8; s >= 1; s >>= 1) ssum += __shfl_xor(ssum, s, 16);
    out[g * 16 + c] = e / ssum;
}

extern "C" void kernel_launch(void* const* d_in, const int* in_sizes, int n_in,
                              void* d_out, int out_size, void* d_ws, size_t ws_size,
                              hipStream_t stream) {
    const float* x    = (const float*)d_in[0];
    const int*   edge = (const int*)d_in[1];
    const int*   batch= (const int*)d_in[2];
    const float* W0   = (const float*)d_in[3];
    const float* b0   = (const float*)d_in[4];
    const float* W1   = (const float*)d_in[5];
    const float* b1   = (const float*)d_in[6];
    const float* W2   = (const float*)d_in[7];
    const float* b2   = (const float*)d_in[8];
    const float* linW = (const float*)d_in[9];
    const float* linb = (const float*)d_in[10];

    int n  = in_sizes[0] / NF;       // 50000
    int ne = in_sizes[1] / 2;        // 800000
    int n_graphs = out_size / 16;    // 64
    const int* row  = edge;
    const int* colv = edge + ne;
    int etot = ne + n;
    int nbuck = (n + 127) >> 7;      // 391

    char* p = (char*)d_ws;
    auto alloc = [&](size_t bytes) { char* r = p; p += (bytes + 255) & ~(size_t)255; return r; };
    int*   bucket_cursor = (int*)alloc((size_t)(MAXBUCK + 1) * 4);
    unsigned int* buck_arr = (unsigned int*)alloc((size_t)MAXBUCK * CAP * 4);
    unsigned short* src16  = (unsigned short*)alloc((size_t)MAXBUCK * CAP * 2);
    int*   starts  = (int*)  alloc((size_t)n * 4);
    int*   ends    = (int*)  alloc((size_t)n * 4);
    float* dinv    = (float*)alloc((size_t)n * 4);
    unsigned short* gbuf = (unsigned short*)alloc((size_t)n * NF * 2);
    unsigned short* abuf = (unsigned short*)alloc((size_t)n * NF * 2);
    float* pooled  = (float*)alloc((size_t)n_graphs * NF * 4);
    unsigned short* whi = (unsigned short*)alloc((size_t)3 * NF * NF * 2);
    unsigned short* wlo = (unsigned short*)alloc((size_t)3 * NF * NF * 2);

    // CSR build (slab buckets: no histogram/scan kernels needed)
    k_binit<<<2, 512, 0, stream>>>(bucket_cursor, nbuck);
    k_bucket_scatter<<<(etot + L1_CHUNK - 1) / L1_CHUNK, L1_THREADS, 0, stream>>>(
        row, colv, bucket_cursor, buck_arr, ne, etot, nbuck);
    k_fine<<<nbuck, 256, 0, stream>>>(buck_arr, bucket_cursor, starts, ends, dinv, src16, n);

    // weight repack (hi/lo split), all 3 in one launch
    k_repack_w3<<<24, 256, 0, stream>>>(W0, W1, W2, whi, wlo);

    int gemm_blocks = (n + 63) / 64;
    int agg_blocks  = (n + 3) / 4;
    const size_t WSLAB = (size_t)NF * NF;

    k_gemm_mfma<<<gemm_blocks, 256, 0, stream>>>(x, nullptr, whi, wlo, dinv, gbuf, n);
    k_agg_bf16 <<<agg_blocks, 256, 0, stream>>>(gbuf, starts, ends, src16, dinv, b0, abuf, n, 1);
    k_gemm_mfma<<<gemm_blocks, 256, 0, stream>>>(nullptr, abuf, whi + WSLAB, wlo + WSLAB, dinv, gbuf, n);
    k_agg_bf16 <<<agg_blocks, 256, 0, stream>>>(gbuf, starts, ends, src16, dinv, b1, abuf, n, 1);
    k_gemm_mfma<<<gemm_blocks, 256, 0, stream>>>(nullptr, abuf, whi + 2 * WSLAB, wlo + 2 * WSLAB, dinv, gbuf, n);
    k_agg_bf16 <<<agg_blocks, 256, 0, stream>>>(gbuf, starts, ends, src16, dinv, b2, abuf, n, 0);

    // pool + head
    hipMemsetAsync(pooled, 0, (size_t)n_graphs * NF * 4, stream);
    int pool_blocks = 400;
    int pool_chunk  = (n + pool_blocks - 1) / pool_blocks;
    k_pool_partial<<<pool_blocks, 128, 0, stream>>>(abuf, batch, pooled, n, pool_chunk);
    k_head<<<1, 1024, 0, stream>>>(pooled, batch, linW, linb, (float*)d_out, n);
}

// Round 9
// 314.707 us; speedup vs baseline: 1.1259x; 1.0164x over previous
//
#include <hip/hip_runtime.h>

// GCN: 3x (GEMM 128x128 + normalized scatter-sum) + mean-pool + linear + softmax.
// R1: two-stage pool. R2: parallel scan. R3: bf16 + split-W MFMA GEMM.
// R4: agg multi-edge-in-flight; h pre-scaled by dinv (edges carry only src idx).
// R5: CSR via two-level bucket sort. R6 FAILED (fusion cut gather parallelism).
// R7: agg 16 edges in flight; slab CSR (no hist/scan kernels).
// R8: agg 32 edges in flight (mean deg 17 -> one memory round-trip/node);
//     cursors slab-relative + zeroed inside repack (k_binit gone); pooling via
//     deterministic partial slabs (no atomics, no memset dispatch).
// Assumes n <= 65536 (src packed u16), n <= 512*128, bucket load < CAP (8.5σ).

#define NF 128
#define MAXBUCK 512
#define CAP 2560           // slab capacity per bucket (mean 2176, sigma ~45)
#define L1_CHUNK 8192
#define L1_THREADS 512
#define L1_PER_THREAD 16   // L1_CHUNK / L1_THREADS
#define PPG 8              // pool partials per graph

typedef __attribute__((ext_vector_type(8))) short short8;
typedef __attribute__((ext_vector_type(4))) float floatx4;

__device__ __forceinline__ unsigned int bf16_rne(float x) {
    unsigned int u = __float_as_uint(x);
    return (u + 0x7fffu + ((u >> 16) & 1u)) >> 16;
}
__device__ __forceinline__ unsigned int pack_bf16_rne(float x, float y) {
    return bf16_rne(x) | (bf16_rne(y) << 16);
}

// ---- repack all 3 W (fp32 [k][n]) into B-fragment-major bf16 hi/lo.
// Block 0 also zeroes the (slab-relative) bucket cursors — runs before scatter. ----
__global__ __launch_bounds__(256) void k_repack_w3(const float* __restrict__ W0,
                                                   const float* __restrict__ W1,
                                                   const float* __restrict__ W2,
                                                   unsigned short* __restrict__ whi,
                                                   unsigned short* __restrict__ wlo,
                                                   int* __restrict__ bucket_cursor) {
    if (blockIdx.x == 0) {
        for (int i = threadIdx.x; i <= MAXBUCK; i += 256) bucket_cursor[i] = 0;
    }
    int wsel = blockIdx.x >> 3;
    const float* W = (wsel == 0) ? W0 : (wsel == 1) ? W1 : W2;
    int idx = (blockIdx.x & 7) * 256 + threadIdx.x;  // 0..2047
    int slab = wsel * NF * NF;
    int l = idx & 63;
    int t = (idx >> 6) & 7;
    int s = idx >> 9;
    int kbase = s * 32 + (l >> 4) * 8;
    int nn = t * 16 + (l & 15);
    #pragma unroll
    for (int j = 0; j < 8; ++j) {
        float w = W[(kbase + j) * NF + nn];
        unsigned int h = bf16_rne(w);
        float hf = __uint_as_float(h << 16);
        unsigned int lo = bf16_rne(w - hf);
        whi[slab + idx * 8 + j] = (unsigned short)h;
        wlo[slab + idx * 8 + j] = (unsigned short)lo;
    }
}

// ---- CSR A: bucket-grouped scatter into fixed slabs via LDS reorder.
// Cursor is slab-relative (zero-initialized); write pos = b*CAP + run + i. ----
__global__ __launch_bounds__(L1_THREADS) void k_bucket_scatter(
        const int* __restrict__ row, const int* __restrict__ colv,
        int* __restrict__ bucket_cursor, unsigned int* __restrict__ buck_arr,
        int ne, int etot, int nbuck) {
    __shared__ unsigned int hist[MAXBUCK];
    __shared__ unsigned int lbase[MAXBUCK];
    __shared__ unsigned int lcur[MAXBUCK];
    __shared__ unsigned int runb[MAXBUCK];
    __shared__ unsigned int sa[MAXBUCK], sb[MAXBUCK];
    __shared__ unsigned int reorder[L1_CHUNK];
    int t = threadIdx.x;
    int e0 = blockIdx.x * L1_CHUNK;
    int cnt_here = min(etot - e0, L1_CHUNK);

    hist[t] = 0;
    __syncthreads();

    unsigned int myv[L1_PER_THREAD];
    #pragma unroll
    for (int j = 0; j < L1_PER_THREAD; ++j) {
        int e = e0 + j * L1_THREADS + t;
        if (e < etot) {
            int s, d;
            if (e < ne) { s = row[e]; d = colv[e]; } else { s = d = e - ne; }
            myv[j] = (unsigned int)s | ((unsigned int)d << 16);
            atomicAdd(&hist[d >> 7], 1u);
        } else myv[j] = 0xffffffffu;
    }
    __syncthreads();

    sa[t] = hist[t];
    __syncthreads();
    unsigned int* pin = sa;
    unsigned int* pout = sb;
    #pragma unroll
    for (int off = 1; off < MAXBUCK; off <<= 1) {
        pout[t] = pin[t] + ((t >= off) ? pin[t - off] : 0);
        __syncthreads();
        unsigned int* tmp = pin; pin = pout; pout = tmp;
    }
    unsigned int ex = pin[t] - hist[t];
    lbase[t] = ex;
    lcur[t]  = ex;
    if (t < nbuck && hist[t] > 0)
        runb[t] = (unsigned int)atomicAdd(&bucket_cursor[t], (int)hist[t]);
    __syncthreads();

    #pragma unroll
    for (int j = 0; j < L1_PER_THREAD; ++j) {
        unsigned int v = myv[j];
        if (v != 0xffffffffu) {
            unsigned int p = atomicAdd(&lcur[v >> 23], 1u);
            reorder[p] = v;
        }
    }
    __syncthreads();

    for (int i = t; i < cnt_here; i += L1_THREADS) {
        unsigned int v = reorder[i];
        unsigned int b = v >> 23;
        buck_arr[(size_t)b * CAP + runb[b] + ((unsigned int)i - lbase[b])] = v;
    }
}

// ---- CSR B: per-bucket fine sort; emits src16 (slab-local), starts/ends/dinv ----
__global__ __launch_bounds__(256) void k_fine(const unsigned int* __restrict__ buck_arr,
                                              const int* __restrict__ bucket_cursor,
                                              int* __restrict__ starts,
                                              int* __restrict__ ends,
                                              float* __restrict__ dinv,
                                              unsigned short* __restrict__ src16,
                                              int n) {
    int b = blockIdx.x;
    int base = b * CAP;
    int m = min(bucket_cursor[b], CAP);
    int node0 = b << 7;
    int nn = min(128, n - node0);
    __shared__ unsigned int cnt[128];
    __shared__ unsigned int lsc[256];
    __shared__ unsigned int lcur[128];
    __shared__ unsigned short srcbuf[CAP];
    int t = threadIdx.x;
    if (t < 128) cnt[t] = 0;
    __syncthreads();
    for (int i = t; i < m; i += 256)
        atomicAdd(&cnt[(buck_arr[base + i] >> 16) - node0], 1u);
    __syncthreads();
    unsigned int v0 = (t < 128) ? cnt[t] : 0;
    lsc[t] = v0;
    __syncthreads();
    #pragma unroll
    for (int off = 1; off < 128; off <<= 1) {
        unsigned int add = (t >= off) ? lsc[t - off] : 0;
        __syncthreads();
        lsc[t] += add;
        __syncthreads();
    }
    if (t < 128) {
        unsigned int ex = lsc[t] - v0;
        lcur[t] = ex;
        if (t < nn) {
            starts[node0 + t] = base + (int)ex;
            ends[node0 + t]   = base + (int)(ex + v0);
            dinv[node0 + t]   = rsqrtf((float)v0);   // deg >= 1 (self-loop)
        }
    }
    __syncthreads();
    for (int i = t; i < m; i += 256) {
        unsigned int v = buck_arr[base + i];
        unsigned int p = atomicAdd(&lcur[(v >> 16) - node0], 1u);
        srcbuf[p] = (unsigned short)(v & 0xffffu);
    }
    __syncthreads();
    for (int i = t; i < m; i += 256)
        src16[base + i] = srcbuf[i];
}

// ---- GEMM: Out[M,128](bf16, pre-scaled by dinv[row]) = A @ (Whi+Wlo) ----
__global__ __launch_bounds__(256) void k_gemm_mfma(const float* __restrict__ Af,
                                                   const unsigned short* __restrict__ Ab,
                                                   const unsigned short* __restrict__ Whi,
                                                   const unsigned short* __restrict__ Wlo,
                                                   const float* __restrict__ dinv,
                                                   unsigned short* __restrict__ Out,
                                                   int M) {
    __shared__ unsigned short As[64 * 136];
    int tid = threadIdx.x;
    int row0 = blockIdx.x * 64;

    if (Af) {
        for (int c = tid; c < 1024; c += 256) {
            int r = c >> 4, off = c & 15;
            int gr = min(row0 + r, M - 1);
            const float4* p = (const float4*)(Af + (size_t)gr * NF) + off * 2;
            float4 v0 = p[0], v1 = p[1];
            uint4 pk;
            pk.x = pack_bf16_rne(v0.x, v0.y);
            pk.y = pack_bf16_rne(v0.z, v0.w);
            pk.z = pack_bf16_rne(v1.x, v1.y);
            pk.w = pack_bf16_rne(v1.z, v1.w);
            *(uint4*)(&As[r * 136 + off * 8]) = pk;
        }
    } else {
        for (int c = tid; c < 1024; c += 256) {
            int r = c >> 4, off = c & 15;
            int gr = min(row0 + r, M - 1);
            *(uint4*)(&As[r * 136 + off * 8]) = ((const uint4*)(Ab + (size_t)gr * NF))[off];
        }
    }
    __syncthreads();

    int wave = tid >> 6, l = tid & 63;
    int q = l >> 4, c16 = l & 15;
    int wrow0 = wave * 16;

    floatx4 acc[8];
    #pragma unroll
    for (int t = 0; t < 8; ++t) acc[t] = (floatx4){0.f, 0.f, 0.f, 0.f};

    #pragma unroll
    for (int s = 0; s < 4; ++s) {
        short8 a = *(const short8*)(&As[(wrow0 + c16) * 136 + s * 32 + q * 8]);
        #pragma unroll
        for (int t = 0; t < 8; ++t) {
            short8 bh = *(const short8*)(Whi + ((size_t)((s * 8 + t) * 64 + l) * 8));
            acc[t] = __builtin_amdgcn_mfma_f32_16x16x32_bf16(a, bh, acc[t], 0, 0, 0);
            short8 bl = *(const short8*)(Wlo + ((size_t)((s * 8 + t) * 64 + l) * 8));
            acc[t] = __builtin_amdgcn_mfma_f32_16x16x32_bf16(a, bl, acc[t], 0, 0, 0);
        }
    }

    float ds[4];
    #pragma unroll
    for (int i = 0; i < 4; ++i) {
        int gr = row0 + wrow0 + q * 4 + i;
        ds[i] = (gr < M) ? dinv[gr] : 0.f;
    }
    #pragma unroll
    for (int t = 0; t < 8; ++t) {
        #pragma unroll
        for (int i = 0; i < 4; ++i) {
            int gr = row0 + wrow0 + q * 4 + i;
            if (gr < M)
                Out[(size_t)gr * NF + t * 16 + c16] =
                    (unsigned short)bf16_rne(acc[t][i] * ds[i]);
        }
    }
}

// ---- out[i] = relu?( dinv[i] * sum_e h'[src_e] + b ). One wave/node;
// lane = (slot g=l>>4, feat f=l&15); uint4/lane; 4 slots x unroll 8 =
// 32 edges in flight (mean deg 17 -> one round-trip). Tail via 0/1 fma mask. ----
__global__ __launch_bounds__(256) void k_agg_bf16(const unsigned short* __restrict__ hs,
                                                  const int* __restrict__ starts,
                                                  const int* __restrict__ ends,
                                                  const unsigned short* __restrict__ src16,
                                                  const float* __restrict__ dinv,
                                                  const float* __restrict__ bias,
                                                  unsigned short* __restrict__ out,
                                                  int n, int do_relu) {
    int wave = threadIdx.x >> 6;
    int lane = threadIdx.x & 63;
    int node = blockIdx.x * 4 + wave;
    if (node >= n) return;
    int g = lane >> 4;
    int f = lane & 15;
    int start = starts[node], end = ends[node];

    const uint4* h4 = (const uint4*)hs;
    float acc[8];
    #pragma unroll
    for (int j = 0; j < 8; ++j) acc[j] = 0.f;

    for (int base = start; base < end; base += 32) {
        int   sidx[8];
        float msk[8];
        #pragma unroll
        for (int j = 0; j < 8; ++j) {
            int e = base + g + 4 * j;
            bool v = e < end;
            sidx[j] = (int)src16[v ? e : start];
            msk[j]  = v ? 1.f : 0.f;
        }
        uint4 rr[8];
        #pragma unroll
        for (int j = 0; j < 8; ++j)
            rr[j] = h4[(size_t)sidx[j] * 16 + f];
        #pragma unroll
        for (int j = 0; j < 8; ++j) {
            const unsigned int* w = (const unsigned int*)&rr[j];
            float m = msk[j];
            #pragma unroll
            for (int k = 0; k < 4; ++k) {
                acc[2 * k]     = fmaf(m, __uint_as_float(w[k] << 16),         acc[2 * k]);
                acc[2 * k + 1] = fmaf(m, __uint_as_float(w[k] & 0xffff0000u), acc[2 * k + 1]);
            }
        }
    }

    // fold the 4 edge slots (lanes 16 apart hold the same feat group)
    #pragma unroll
    for (int j = 0; j < 8; ++j) {
        acc[j] += __shfl_xor(acc[j], 16);
        acc[j] += __shfl_xor(acc[j], 32);
    }

    if (g == 0) {
        float dd = dinv[node];
        float4 b0 = ((const float4*)bias)[2 * f];
        float4 b1 = ((const float4*)bias)[2 * f + 1];
        float r[8];
        r[0] = fmaf(dd, acc[0], b0.x); r[1] = fmaf(dd, acc[1], b0.y);
        r[2] = fmaf(dd, acc[2], b0.z); r[3] = fmaf(dd, acc[3], b0.w);
        r[4] = fmaf(dd, acc[4], b1.x); r[5] = fmaf(dd, acc[5], b1.y);
        r[6] = fmaf(dd, acc[6], b1.z); r[7] = fmaf(dd, acc[7], b1.w);
        if (do_relu) {
            #pragma unroll
            for (int j = 0; j < 8; ++j) r[j] = fmaxf(r[j], 0.f);
        }
        uint4 pk;
        pk.x = pack_bf16_rne(r[0], r[1]);
        pk.y = pack_bf16_rne(r[2], r[3]);
        pk.z = pack_bf16_rne(r[4], r[5]);
        pk.w = pack_bf16_rne(r[6], r[7]);
        ((uint4*)out)[(size_t)node * 16 + f] = pk;
    }
}

// ---- pooling: deterministic partial slabs — block (g, j) sums slice j of
// graph g's node range (batch sorted; binary search). No atomics, no memset:
// every slot written unconditionally. ----
__global__ __launch_bounds__(128) void k_pool_partial(const unsigned short* __restrict__ h,
                                                      const int* __restrict__ batch,
                                                      float* __restrict__ pooled_part,
                                                      int n) {
    int b = blockIdx.x;
    int g = b / PPG;
    int j = b % PPG;
    int t = threadIdx.x;

    int lo = 0, hi = n;
    while (lo < hi) { int mid = (lo + hi) >> 1; if (batch[mid] < g) lo = mid + 1; else hi = mid; }
    int s = lo;
    lo = s; hi = n;
    while (lo < hi) { int mid = (lo + hi) >> 1; if (batch[mid] < g + 1) lo = mid + 1; else hi = mid; }
    int e = lo;

    int len = e - s;
    int chunk = (len + PPG - 1) / PPG;
    int i0 = s + j * chunk;
    int i1 = min(e, i0 + chunk);

    float acc = 0.f;
    for (int i = i0; i < i1; ++i)
        acc += __uint_as_float((unsigned int)h[(size_t)i * NF + t] << 16);
    pooled_part[(size_t)b * NF + t] = acc;
}

// ---- head: fold partials in LDS, counts + linear 128x16 + softmax ----
__global__ __launch_bounds__(1024) void k_head(const float* __restrict__ pooled_part,
                                               const int* __restrict__ batch,
                                               const float* __restrict__ linW,
                                               const float* __restrict__ linb,
                                               float* __restrict__ out,
                                               int n, int n_graphs) {
    __shared__ float ph[64 * NF];  // 32 KB
    int t = threadIdx.x;
    for (int i = t; i < n_graphs * NF; i += 1024) {
        int g = i >> 7, f = i & 127;
        float s = 0.f;
        #pragma unroll
        for (int j = 0; j < PPG; ++j)
            s += pooled_part[(size_t)(g * PPG + j) * NF + f];
        ph[i] = s;
    }
    __syncthreads();

    int g = t >> 4;
    int c = t & 15;

    int lo = 0, hi = n;
    while (lo < hi) { int mid = (lo + hi) >> 1; if (batch[mid] < g) lo = mid + 1; else hi = mid; }
    int start = lo;
    lo = start; hi = n;
    while (lo < hi) { int mid = (lo + hi) >> 1; if (batch[mid] < g + 1) lo = mid + 1; else hi = mid; }
    float inv_cnt = 1.f / fmaxf((float)(lo - start), 1.f);

    float acc = linb[c];
    for (int k = 0; k < NF; ++k)
        acc += ph[g * NF + k] * inv_cnt * linW[k * 16 + c];

    float m = acc;
    #pragma unroll
    for (int s2 = 8; s2 >= 1; s2 >>= 1) m = fmaxf(m, __shfl_xor(m, s2, 16));
    float e = expf(acc - m);
    float ssum = e;
    #pragma unroll
    for (int s2 = 8; s2 >= 1; s2 >>= 1) ssum += __shfl_xor(ssum, s2, 16);
    out[g * 16 + c] = e / ssum;
}

extern "C" void kernel_launch(void* const* d_in, const int* in_sizes, int n_in,
                              void* d_out, int out_size, void* d_ws, size_t ws_size,
                              hipStream_t stream) {
    const float* x    = (const float*)d_in[0];
    const int*   edge = (const int*)d_in[1];
    const int*   batch= (const int*)d_in[2];
    const float* W0   = (const float*)d_in[3];
    const float* b0   = (const float*)d_in[4];
    const float* W1   = (const float*)d_in[5];
    const float* b1   = (const float*)d_in[6];
    const float* W2   = (const float*)d_in[7];
    const float* b2   = (const float*)d_in[8];
    const float* linW = (const float*)d_in[9];
    const float* linb = (const float*)d_in[10];

    int n  = in_sizes[0] / NF;       // 50000
    int ne = in_sizes[1] / 2;        // 800000
    int n_graphs = out_size / 16;    // 64
    const int* row  = edge;
    const int* colv = edge + ne;
    int etot = ne + n;
    int nbuck = (n + 127) >> 7;      // 391

    char* p = (char*)d_ws;
    auto alloc = [&](size_t bytes) { char* r = p; p += (bytes + 255) & ~(size_t)255; return r; };
    int*   bucket_cursor = (int*)alloc((size_t)(MAXBUCK + 1) * 4);
    unsigned int* buck_arr = (unsigned int*)alloc((size_t)MAXBUCK * CAP * 4);
    unsigned short* src16  = (unsigned short*)alloc((size_t)MAXBUCK * CAP * 2);
    int*   starts  = (int*)  alloc((size_t)n * 4);
    int*   ends    = (int*)  alloc((size_t)n * 4);
    float* dinv    = (float*)alloc((size_t)n * 4);
    unsigned short* gbuf = (unsigned short*)alloc((size_t)n * NF * 2);
    unsigned short* abuf = (unsigned short*)alloc((size_t)n * NF * 2);
    float* pooled_part = (float*)alloc((size_t)n_graphs * PPG * NF * 4);
    unsigned short* whi = (unsigned short*)alloc((size_t)3 * NF * NF * 2);
    unsigned short* wlo = (unsigned short*)alloc((size_t)3 * NF * NF * 2);

    // repack first (block 0 also zeroes bucket cursors)
    k_repack_w3<<<24, 256, 0, stream>>>(W0, W1, W2, whi, wlo, bucket_cursor);

    // CSR build (slab buckets)
    k_bucket_scatter<<<(etot + L1_CHUNK - 1) / L1_CHUNK, L1_THREADS, 0, stream>>>(
        row, colv, bucket_cursor, buck_arr, ne, etot, nbuck);
    k_fine<<<nbuck, 256, 0, stream>>>(buck_arr, bucket_cursor, starts, ends, dinv, src16, n);

    int gemm_blocks = (n + 63) / 64;
    int agg_blocks  = (n + 3) / 4;
    const size_t WSLAB = (size_t)NF * NF;

    k_gemm_mfma<<<gemm_blocks, 256, 0, stream>>>(x, nullptr, whi, wlo, dinv, gbuf, n);
    k_agg_bf16 <<<agg_blocks, 256, 0, stream>>>(gbuf, starts, ends, src16, dinv, b0, abuf, n, 1);
    k_gemm_mfma<<<gemm_blocks, 256, 0, stream>>>(nullptr, abuf, whi + WSLAB, wlo + WSLAB, dinv, gbuf, n);
    k_agg_bf16 <<<agg_blocks, 256, 0, stream>>>(gbuf, starts, ends, src16, dinv, b1, abuf, n, 1);
    k_gemm_mfma<<<gemm_blocks, 256, 0, stream>>>(nullptr, abuf, whi + 2 * WSLAB, wlo + 2 * WSLAB, dinv, gbuf, n);
    k_agg_bf16 <<<agg_blocks, 256, 0, stream>>>(gbuf, starts, ends, src16, dinv, b2, abuf, n, 0);

    // pool (no atomics/memset) + head
    k_pool_partial<<<n_graphs * PPG, 128, 0, stream>>>(abuf, batch, pooled_part, n);
    k_head<<<1, 1024, 0, stream>>>(pooled_part, batch, linW, linb, (float*)d_out, n, n_graphs);
}

// Round 10
// 292.379 us; speedup vs baseline: 1.2119x; 1.0764x over previous
//
#include <hip/hip_runtime.h>

// GCN: 3x (GEMM 128x128 + normalized scatter-sum) + mean-pool + linear + softmax.
// R1: two-stage pool. R2: parallel scan. R3: bf16 + split-W MFMA GEMM.
// R4: agg multi-edge-in-flight; h pre-scaled by dinv (edges carry only src idx).
// R5: CSR via two-level bucket sort. R6 FAILED (fusion cut gather parallelism).
// R7: agg 16 edges in flight; slab CSR. R8: 32 edges in flight; atomic/memset-free pool.
// R9: gbuf (the randomly-gathered buffer) stored as OCP fp8 e4m3 — halves the
//     218MB/layer gather traffic (agg is BW-bound per R8 neutrality). Decode via
//     v_cvt_pk_f32_fp8 in agg; encode in gemm epilogue. Accumulation stays f32,
//     A-matrix/abuf stay bf16, so only gather-payload precision drops; pool
//     averaging (~13k draws/graph) shrinks the fp8 noise ~100x.
// Assumes n <= 65536 (src packed u16), n <= 512*128, bucket load < CAP (8.5σ).

#define NF 128
#define MAXBUCK 512
#define CAP 2560           // slab capacity per bucket (mean 2176, sigma ~45)
#define L1_CHUNK 8192
#define L1_THREADS 512
#define L1_PER_THREAD 16   // L1_CHUNK / L1_THREADS
#define PPG 8              // pool partials per graph

typedef __attribute__((ext_vector_type(8))) short short8;
typedef __attribute__((ext_vector_type(4))) float floatx4;
typedef __attribute__((ext_vector_type(2))) float floatx2;

__device__ __forceinline__ unsigned int bf16_rne(float x) {
    unsigned int u = __float_as_uint(x);
    return (u + 0x7fffu + ((u >> 16) & 1u)) >> 16;
}
__device__ __forceinline__ unsigned int pack_bf16_rne(float x, float y) {
    return bf16_rne(x) | (bf16_rne(y) << 16);
}

// ---- repack all 3 W (fp32 [k][n]) into B-fragment-major bf16 hi/lo.
// Block 0 also zeroes the (slab-relative) bucket cursors — runs before scatter. ----
__global__ __launch_bounds__(256) void k_repack_w3(const float* __restrict__ W0,
                                                   const float* __restrict__ W1,
                                                   const float* __restrict__ W2,
                                                   unsigned short* __restrict__ whi,
                                                   unsigned short* __restrict__ wlo,
                                                   int* __restrict__ bucket_cursor) {
    if (blockIdx.x == 0) {
        for (int i = threadIdx.x; i <= MAXBUCK; i += 256) bucket_cursor[i] = 0;
    }
    int wsel = blockIdx.x >> 3;
    const float* W = (wsel == 0) ? W0 : (wsel == 1) ? W1 : W2;
    int idx = (blockIdx.x & 7) * 256 + threadIdx.x;  // 0..2047
    int slab = wsel * NF * NF;
    int l = idx & 63;
    int t = (idx >> 6) & 7;
    int s = idx >> 9;
    int kbase = s * 32 + (l >> 4) * 8;
    int nn = t * 16 + (l & 15);
    #pragma unroll
    for (int j = 0; j < 8; ++j) {
        float w = W[(kbase + j) * NF + nn];
        unsigned int h = bf16_rne(w);
        float hf = __uint_as_float(h << 16);
        unsigned int lo = bf16_rne(w - hf);
        whi[slab + idx * 8 + j] = (unsigned short)h;
        wlo[slab + idx * 8 + j] = (unsigned short)lo;
    }
}

// ---- CSR A: bucket-grouped scatter into fixed slabs via LDS reorder ----
__global__ __launch_bounds__(L1_THREADS) void k_bucket_scatter(
        const int* __restrict__ row, const int* __restrict__ colv,
        int* __restrict__ bucket_cursor, unsigned int* __restrict__ buck_arr,
        int ne, int etot, int nbuck) {
    __shared__ unsigned int hist[MAXBUCK];
    __shared__ unsigned int lbase[MAXBUCK];
    __shared__ unsigned int lcur[MAXBUCK];
    __shared__ unsigned int runb[MAXBUCK];
    __shared__ unsigned int sa[MAXBUCK], sb[MAXBUCK];
    __shared__ unsigned int reorder[L1_CHUNK];
    int t = threadIdx.x;
    int e0 = blockIdx.x * L1_CHUNK;
    int cnt_here = min(etot - e0, L1_CHUNK);

    hist[t] = 0;
    __syncthreads();

    unsigned int myv[L1_PER_THREAD];
    #pragma unroll
    for (int j = 0; j < L1_PER_THREAD; ++j) {
        int e = e0 + j * L1_THREADS + t;
        if (e < etot) {
            int s, d;
            if (e < ne) { s = row[e]; d = colv[e]; } else { s = d = e - ne; }
            myv[j] = (unsigned int)s | ((unsigned int)d << 16);
            atomicAdd(&hist[d >> 7], 1u);
        } else myv[j] = 0xffffffffu;
    }
    __syncthreads();

    sa[t] = hist[t];
    __syncthreads();
    unsigned int* pin = sa;
    unsigned int* pout = sb;
    #pragma unroll
    for (int off = 1; off < MAXBUCK; off <<= 1) {
        pout[t] = pin[t] + ((t >= off) ? pin[t - off] : 0);
        __syncthreads();
        unsigned int* tmp = pin; pin = pout; pout = tmp;
    }
    unsigned int ex = pin[t] - hist[t];
    lbase[t] = ex;
    lcur[t]  = ex;
    if (t < nbuck && hist[t] > 0)
        runb[t] = (unsigned int)atomicAdd(&bucket_cursor[t], (int)hist[t]);
    __syncthreads();

    #pragma unroll
    for (int j = 0; j < L1_PER_THREAD; ++j) {
        unsigned int v = myv[j];
        if (v != 0xffffffffu) {
            unsigned int p = atomicAdd(&lcur[v >> 23], 1u);
            reorder[p] = v;
        }
    }
    __syncthreads();

    for (int i = t; i < cnt_here; i += L1_THREADS) {
        unsigned int v = reorder[i];
        unsigned int b = v >> 23;
        buck_arr[(size_t)b * CAP + runb[b] + ((unsigned int)i - lbase[b])] = v;
    }
}

// ---- CSR B: per-bucket fine sort; emits src16 (slab-local), starts/ends/dinv ----
__global__ __launch_bounds__(256) void k_fine(const unsigned int* __restrict__ buck_arr,
                                              const int* __restrict__ bucket_cursor,
                                              int* __restrict__ starts,
                                              int* __restrict__ ends,
                                              float* __restrict__ dinv,
                                              unsigned short* __restrict__ src16,
                                              int n) {
    int b = blockIdx.x;
    int base = b * CAP;
    int m = min(bucket_cursor[b], CAP);
    int node0 = b << 7;
    int nn = min(128, n - node0);
    __shared__ unsigned int cnt[128];
    __shared__ unsigned int lsc[256];
    __shared__ unsigned int lcur[128];
    __shared__ unsigned short srcbuf[CAP];
    int t = threadIdx.x;
    if (t < 128) cnt[t] = 0;
    __syncthreads();
    for (int i = t; i < m; i += 256)
        atomicAdd(&cnt[(buck_arr[base + i] >> 16) - node0], 1u);
    __syncthreads();
    unsigned int v0 = (t < 128) ? cnt[t] : 0;
    lsc[t] = v0;
    __syncthreads();
    #pragma unroll
    for (int off = 1; off < 128; off <<= 1) {
        unsigned int add = (t >= off) ? lsc[t - off] : 0;
        __syncthreads();
        lsc[t] += add;
        __syncthreads();
    }
    if (t < 128) {
        unsigned int ex = lsc[t] - v0;
        lcur[t] = ex;
        if (t < nn) {
            starts[node0 + t] = base + (int)ex;
            ends[node0 + t]   = base + (int)(ex + v0);
            dinv[node0 + t]   = rsqrtf((float)v0);   // deg >= 1 (self-loop)
        }
    }
    __syncthreads();
    for (int i = t; i < m; i += 256) {
        unsigned int v = buck_arr[base + i];
        unsigned int p = atomicAdd(&lcur[(v >> 16) - node0], 1u);
        srcbuf[p] = (unsigned short)(v & 0xffffu);
    }
    __syncthreads();
    for (int i = t; i < m; i += 256)
        src16[base + i] = srcbuf[i];
}

// ---- GEMM: Out[M,128](fp8 e4m3, pre-scaled by dinv[row]) = A @ (Whi+Wlo) ----
__global__ __launch_bounds__(256) void k_gemm_mfma(const float* __restrict__ Af,
                                                   const unsigned short* __restrict__ Ab,
                                                   const unsigned short* __restrict__ Whi,
                                                   const unsigned short* __restrict__ Wlo,
                                                   const float* __restrict__ dinv,
                                                   unsigned char* __restrict__ Out,
                                                   int M) {
    __shared__ unsigned short As[64 * 136];
    int tid = threadIdx.x;
    int row0 = blockIdx.x * 64;

    if (Af) {
        for (int c = tid; c < 1024; c += 256) {
            int r = c >> 4, off = c & 15;
            int gr = min(row0 + r, M - 1);
            const float4* p = (const float4*)(Af + (size_t)gr * NF) + off * 2;
            float4 v0 = p[0], v1 = p[1];
            uint4 pk;
            pk.x = pack_bf16_rne(v0.x, v0.y);
            pk.y = pack_bf16_rne(v0.z, v0.w);
            pk.z = pack_bf16_rne(v1.x, v1.y);
            pk.w = pack_bf16_rne(v1.z, v1.w);
            *(uint4*)(&As[r * 136 + off * 8]) = pk;
        }
    } else {
        for (int c = tid; c < 1024; c += 256) {
            int r = c >> 4, off = c & 15;
            int gr = min(row0 + r, M - 1);
            *(uint4*)(&As[r * 136 + off * 8]) = ((const uint4*)(Ab + (size_t)gr * NF))[off];
        }
    }
    __syncthreads();

    int wave = tid >> 6, l = tid & 63;
    int q = l >> 4, c16 = l & 15;
    int wrow0 = wave * 16;

    floatx4 acc[8];
    #pragma unroll
    for (int t = 0; t < 8; ++t) acc[t] = (floatx4){0.f, 0.f, 0.f, 0.f};

    #pragma unroll
    for (int s = 0; s < 4; ++s) {
        short8 a = *(const short8*)(&As[(wrow0 + c16) * 136 + s * 32 + q * 8]);
        #pragma unroll
        for (int t = 0; t < 8; ++t) {
            short8 bh = *(const short8*)(Whi + ((size_t)((s * 8 + t) * 64 + l) * 8));
            acc[t] = __builtin_amdgcn_mfma_f32_16x16x32_bf16(a, bh, acc[t], 0, 0, 0);
            short8 bl = *(const short8*)(Wlo + ((size_t)((s * 8 + t) * 64 + l) * 8));
            acc[t] = __builtin_amdgcn_mfma_f32_16x16x32_bf16(a, bl, acc[t], 0, 0, 0);
        }
    }

    float ds[4];
    #pragma unroll
    for (int i = 0; i < 4; ++i) {
        int gr = row0 + wrow0 + q * 4 + i;
        ds[i] = (gr < M) ? dinv[gr] : 0.f;
    }
    #pragma unroll
    for (int t = 0; t < 8; ++t) {
        #pragma unroll
        for (int i = 0; i < 4; ++i) {
            int gr = row0 + wrow0 + q * 4 + i;
            if (gr < M) {
                float v = acc[t][i] * ds[i];
                unsigned int pk = __builtin_amdgcn_cvt_pk_fp8_f32(v, v, 0, false);
                Out[(size_t)gr * NF + t * 16 + c16] = (unsigned char)(pk & 0xffu);
            }
        }
    }
}

// ---- out[i] = relu?( dinv[i] * sum_e h8[src_e] + b ), h8 fp8 pre-scaled.
// One wave/node; lane = (slot g=l>>4, feat f=l&15); uint2 (8 fp8 feats)/lane;
// 4 slots x unroll 8 = 32 edges in flight. Tail via 0/1 fma mask. ----
__global__ __launch_bounds__(256) void k_agg_fp8(const unsigned char* __restrict__ hs8,
                                                 const int* __restrict__ starts,
                                                 const int* __restrict__ ends,
                                                 const unsigned short* __restrict__ src16,
                                                 const float* __restrict__ dinv,
                                                 const float* __restrict__ bias,
                                                 unsigned short* __restrict__ out,
                                                 int n, int do_relu) {
    int wave = threadIdx.x >> 6;
    int lane = threadIdx.x & 63;
    int node = blockIdx.x * 4 + wave;
    if (node >= n) return;
    int g = lane >> 4;
    int f = lane & 15;
    int start = starts[node], end = ends[node];

    const uint2* h2 = (const uint2*)hs8;   // 16 uint2 per 128-feat fp8 row
    float acc[8];
    #pragma unroll
    for (int j = 0; j < 8; ++j) acc[j] = 0.f;

    for (int base = start; base < end; base += 32) {
        int   sidx[8];
        float msk[8];
        #pragma unroll
        for (int j = 0; j < 8; ++j) {
            int e = base + g + 4 * j;
            bool v = e < end;
            sidx[j] = (int)src16[v ? e : start];  // masked slots reload a VALID row (no NaN decode)
            msk[j]  = v ? 1.f : 0.f;
        }
        uint2 rr[8];
        #pragma unroll
        for (int j = 0; j < 8; ++j)
            rr[j] = h2[(size_t)sidx[j] * 16 + f];
        #pragma unroll
        for (int j = 0; j < 8; ++j) {
            float m = msk[j];
            floatx2 p0 = __builtin_amdgcn_cvt_pk_f32_fp8(rr[j].x, false);
            floatx2 p1 = __builtin_amdgcn_cvt_pk_f32_fp8(rr[j].x, true);
            floatx2 p2 = __builtin_amdgcn_cvt_pk_f32_fp8(rr[j].y, false);
            floatx2 p3 = __builtin_amdgcn_cvt_pk_f32_fp8(rr[j].y, true);
            acc[0] = fmaf(m, p0.x, acc[0]);
            acc[1] = fmaf(m, p0.y, acc[1]);
            acc[2] = fmaf(m, p1.x, acc[2]);
            acc[3] = fmaf(m, p1.y, acc[3]);
            acc[4] = fmaf(m, p2.x, acc[4]);
            acc[5] = fmaf(m, p2.y, acc[5]);
            acc[6] = fmaf(m, p3.x, acc[6]);
            acc[7] = fmaf(m, p3.y, acc[7]);
        }
    }

    // fold the 4 edge slots (lanes 16 apart hold the same feat group)
    #pragma unroll
    for (int j = 0; j < 8; ++j) {
        acc[j] += __shfl_xor(acc[j], 16);
        acc[j] += __shfl_xor(acc[j], 32);
    }

    if (g == 0) {
        float dd = dinv[node];
        float4 b0 = ((const float4*)bias)[2 * f];
        float4 b1 = ((const float4*)bias)[2 * f + 1];
        float r[8];
        r[0] = fmaf(dd, acc[0], b0.x); r[1] = fmaf(dd, acc[1], b0.y);
        r[2] = fmaf(dd, acc[2], b0.z); r[3] = fmaf(dd, acc[3], b0.w);
        r[4] = fmaf(dd, acc[4], b1.x); r[5] = fmaf(dd, acc[5], b1.y);
        r[6] = fmaf(dd, acc[6], b1.z); r[7] = fmaf(dd, acc[7], b1.w);
        if (do_relu) {
            #pragma unroll
            for (int j = 0; j < 8; ++j) r[j] = fmaxf(r[j], 0.f);
        }
        uint4 pk;
        pk.x = pack_bf16_rne(r[0], r[1]);
        pk.y = pack_bf16_rne(r[2], r[3]);
        pk.z = pack_bf16_rne(r[4], r[5]);
        pk.w = pack_bf16_rne(r[6], r[7]);
        ((uint4*)out)[(size_t)node * 16 + f] = pk;
    }
}

// ---- pooling: deterministic partial slabs (no atomics, no memset) ----
__global__ __launch_bounds__(128) void k_pool_partial(const unsigned short* __restrict__ h,
                                                      const int* __restrict__ batch,
                                                      float* __restrict__ pooled_part,
                                                      int n) {
    int b = blockIdx.x;
    int g = b / PPG;
    int j = b % PPG;
    int t = threadIdx.x;

    int lo = 0, hi = n;
    while (lo < hi) { int mid = (lo + hi) >> 1; if (batch[mid] < g) lo = mid + 1; else hi = mid; }
    int s = lo;
    lo = s; hi = n;
    while (lo < hi) { int mid = (lo + hi) >> 1; if (batch[mid] < g + 1) lo = mid + 1; else hi = mid; }
    int e = lo;

    int len = e - s;
    int chunk = (len + PPG - 1) / PPG;
    int i0 = s + j * chunk;
    int i1 = min(e, i0 + chunk);

    float acc = 0.f;
    for (int i = i0; i < i1; ++i)
        acc += __uint_as_float((unsigned int)h[(size_t)i * NF + t] << 16);
    pooled_part[(size_t)b * NF + t] = acc;
}

// ---- head: fold partials in LDS, counts + linear 128x16 + softmax ----
__global__ __launch_bounds__(1024) void k_head(const float* __restrict__ pooled_part,
                                               const int* __restrict__ batch,
                                               const float* __restrict__ linW,
                                               const float* __restrict__ linb,
                                               float* __restrict__ out,
                                               int n, int n_graphs) {
    __shared__ float ph[64 * NF];  // 32 KB
    int t = threadIdx.x;
    for (int i = t; i < n_graphs * NF; i += 1024) {
        int g = i >> 7, f = i & 127;
        float s = 0.f;
        #pragma unroll
        for (int j = 0; j < PPG; ++j)
            s += pooled_part[(size_t)(g * PPG + j) * NF + f];
        ph[i] = s;
    }
    __syncthreads();

    int g = t >> 4;
    int c = t & 15;

    int lo = 0, hi = n;
    while (lo < hi) { int mid = (lo + hi) >> 1; if (batch[mid] < g) lo = mid + 1; else hi = mid; }
    int start = lo;
    lo = start; hi = n;
    while (lo < hi) { int mid = (lo + hi) >> 1; if (batch[mid] < g + 1) lo = mid + 1; else hi = mid; }
    float inv_cnt = 1.f / fmaxf((float)(lo - start), 1.f);

    float acc = linb[c];
    for (int k = 0; k < NF; ++k)
        acc += ph[g * NF + k] * inv_cnt * linW[k * 16 + c];

    float m = acc;
    #pragma unroll
    for (int s2 = 8; s2 >= 1; s2 >>= 1) m = fmaxf(m, __shfl_xor(m, s2, 16));
    float e = expf(acc - m);
    float ssum = e;
    #pragma unroll
    for (int s2 = 8; s2 >= 1; s2 >>= 1) ssum += __shfl_xor(ssum, s2, 16);
    out[g * 16 + c] = e / ssum;
}

extern "C" void kernel_launch(void* const* d_in, const int* in_sizes, int n_in,
                              void* d_out, int out_size, void* d_ws, size_t ws_size,
                              hipStream_t stream) {
    const float* x    = (const float*)d_in[0];
    const int*   edge = (const int*)d_in[1];
    const int*   batch= (const int*)d_in[2];
    const float* W0   = (const float*)d_in[3];
    const float* b0   = (const float*)d_in[4];
    const float* W1   = (const float*)d_in[5];
    const float* b1   = (const float*)d_in[6];
    const float* W2   = (const float*)d_in[7];
    const float* b2   = (const float*)d_in[8];
    const float* linW = (const float*)d_in[9];
    const float* linb = (const float*)d_in[10];

    int n  = in_sizes[0] / NF;       // 50000
    int ne = in_sizes[1] / 2;        // 800000
    int n_graphs = out_size / 16;    // 64
    const int* row  = edge;
    const int* colv = edge + ne;
    int etot = ne + n;
    int nbuck = (n + 127) >> 7;      // 391

    char* p = (char*)d_ws;
    auto alloc = [&](size_t bytes) { char* r = p; p += (bytes + 255) & ~(size_t)255; return r; };
    int*   bucket_cursor = (int*)alloc((size_t)(MAXBUCK + 1) * 4);
    unsigned int* buck_arr = (unsigned int*)alloc((size_t)MAXBUCK * CAP * 4);
    unsigned short* src16  = (unsigned short*)alloc((size_t)MAXBUCK * CAP * 2);
    int*   starts  = (int*)  alloc((size_t)n * 4);
    int*   ends    = (int*)  alloc((size_t)n * 4);
    float* dinv    = (float*)alloc((size_t)n * 4);
    unsigned char*  gbuf8 = (unsigned char*) alloc((size_t)n * NF);      // fp8 gemm out
    unsigned short* abuf  = (unsigned short*)alloc((size_t)n * NF * 2);  // bf16 agg out
    float* pooled_part = (float*)alloc((size_t)n_graphs * PPG * NF * 4);
    unsigned short* whi = (unsigned short*)alloc((size_t)3 * NF * NF * 2);
    unsigned short* wlo = (unsigned short*)alloc((size_t)3 * NF * NF * 2);

    // repack first (block 0 also zeroes bucket cursors)
    k_repack_w3<<<24, 256, 0, stream>>>(W0, W1, W2, whi, wlo, bucket_cursor);

    // CSR build (slab buckets)
    k_bucket_scatter<<<(etot + L1_CHUNK - 1) / L1_CHUNK, L1_THREADS, 0, stream>>>(
        row, colv, bucket_cursor, buck_arr, ne, etot, nbuck);
    k_fine<<<nbuck, 256, 0, stream>>>(buck_arr, bucket_cursor, starts, ends, dinv, src16, n);

    int gemm_blocks = (n + 63) / 64;
    int agg_blocks  = (n + 3) / 4;
    const size_t WSLAB = (size_t)NF * NF;

    k_gemm_mfma<<<gemm_blocks, 256, 0, stream>>>(x, nullptr, whi, wlo, dinv, gbuf8, n);
    k_agg_fp8  <<<agg_blocks, 256, 0, stream>>>(gbuf8, starts, ends, src16, dinv, b0, abuf, n, 1);
    k_gemm_mfma<<<gemm_blocks, 256, 0, stream>>>(nullptr, abuf, whi + WSLAB, wlo + WSLAB, dinv, gbuf8, n);
    k_agg_fp8  <<<agg_blocks, 256, 0, stream>>>(gbuf8, starts, ends, src16, dinv, b1, abuf, n, 1);
    k_gemm_mfma<<<gemm_blocks, 256, 0, stream>>>(nullptr, abuf, whi + 2 * WSLAB, wlo + 2 * WSLAB, dinv, gbuf8, n);
    k_agg_fp8  <<<agg_blocks, 256, 0, stream>>>(gbuf8, starts, ends, src16, dinv, b2, abuf, n, 0);

    // pool (no atomics/memset) + head
    k_pool_partial<<<n_graphs * PPG, 128, 0, stream>>>(abuf, batch, pooled_part, n);
    k_head<<<1, 1024, 0, stream>>>(pooled_part, batch, linW, linb, (float*)d_out, n, n_graphs);
}